// Round 4
// baseline (238.867 us; speedup 1.0000x reference)
//
#include <hip/hip_runtime.h>
#include <stdint.h>

typedef __attribute__((ext_vector_type(8))) short bf16x8;
typedef __attribute__((ext_vector_type(4))) float f32x4;

#define B_ROWS 131072
#define BM 32
#define NT 8            // tiles per block
#define GRID 512        // 512 * 8 * 32 = 131072 rows
#define ZP 456          // z row pitch in bf16 (448 + 8 pad)
#define AP 136          // a1 row pitch in bf16 (128 + 8 pad)

#define ZBYTES   (BM * ZP * 2)         // 29184
#define A1_OFF   (2 * ZBYTES)          // 58368
#define BIAS_OFF (A1_OFF + BM * AP * 2)// 67072
#define LDET_OFF (BIAS_OFF + 512 * 4)  // 69120
#define LDS_TOTAL (LDET_OFF + 4 * BM * 4) // 69632 -> 2 blocks/CU

// packed weight fragment offsets (uint4 units)
#define W1P_OFF 0      // 8 nt * 14 kt * 64
#define W2P_OFF 7168   // 8 * 4 * 64
#define W3P_OFF 9216   // 16 * 4 * 64

__device__ inline uint16_t f2bf(float x) {
  uint32_t u = __float_as_uint(x);
  u += 0x7fffu + ((u >> 16) & 1u);
  return (uint16_t)(u >> 16);
}

__device__ inline float tanh_fast(float x) {
  x = fminf(fmaxf(x, -15.f), 15.f);
  float e = __expf(2.f * x);
  return (e - 1.f) / (e + 1.f);
}

__global__ void prepack_kernel(const float* __restrict__ W1,
                               const float* __restrict__ W2,
                               const float* __restrict__ W3,
                               uint4* __restrict__ wp) {
  int tid = blockIdx.x * 256 + threadIdx.x;
  if (tid >= 13312) return;
  int l = tid & 63, f = tid >> 6;
  const float* W; int N, kt, nt;
  if (f < 112)      { W = W1; N = 128; int ff = f;       nt = ff / 14; kt = ff - nt * 14; }
  else if (f < 144) { W = W2; N = 128; int ff = f - 112; nt = ff >> 2; kt = ff & 3; }
  else              { W = W3; N = 256; int ff = f - 144; nt = ff >> 2; kt = ff & 3; }
  int k0  = kt * 32 + (l >> 4) * 8;
  int col = nt * 16 + (l & 15);
  uint16_t v[8];
#pragma unroll
  for (int j = 0; j < 8; j++) v[j] = f2bf(W[(size_t)(k0 + j) * N + col]);
  uint4 o;
  o.x = (uint32_t)v[0] | ((uint32_t)v[1] << 16);
  o.y = (uint32_t)v[2] | ((uint32_t)v[3] << 16);
  o.z = (uint32_t)v[4] | ((uint32_t)v[5] << 16);
  o.w = (uint32_t)v[6] | ((uint32_t)v[7] << 16);
  wp[tid] = o;
}

// convert held f32 regs -> bf16 and write into z buffer
__device__ inline void stage_write(uint16_t* zn, int t,
                                   const float4* xr, const float4* hr) {
#pragma unroll
  for (int k = 0; k < 8; k++) {
    int idx = t + k * 256;
    int row = idx >> 6, c4 = idx & 63;
    uint32_t p = (uint32_t)f2bf(xr[k].x) | ((uint32_t)f2bf(xr[k].z) << 16);
    *(uint32_t*)&zn[row * ZP + c4 * 2] = p;
  }
#pragma unroll
  for (int k = 0; k < 10; k++) {
    int idx = t + k * 256;
    int row = idx / 80, c4 = idx - row * 80;
    uint2 p;
    p.x = (uint32_t)f2bf(hr[k].x) | ((uint32_t)f2bf(hr[k].y) << 16);
    p.y = (uint32_t)f2bf(hr[k].z) | ((uint32_t)f2bf(hr[k].w) << 16);
    *(uint2*)&zn[row * ZP + 128 + c4 * 4] = p;
  }
}

__global__ __launch_bounds__(256, 2) void fused_kernel(
    const float* __restrict__ x, const float* __restrict__ h,
    const float* __restrict__ b1, const float* __restrict__ b2,
    const float* __restrict__ b3, const uint4* __restrict__ wp,
    float* __restrict__ y, float* __restrict__ ldet) {
  extern __shared__ uint8_t smem[];
  uint16_t* a1   = (uint16_t*)(smem + A1_OFF);
  float*    bias = (float*)(smem + BIAS_OFF);
  float*    lsum = (float*)(smem + LDET_OFF);

  const int t = threadIdx.x;
  const int wid = t >> 6, l = t & 63;
  const int lr = l & 15, lq = l >> 4;
  const int tile0 = blockIdx.x * NT;

  for (int i = t; i < 512; i += 256)
    bias[i] = (i < 128) ? b1[i] : (i < 256) ? b2[i - 128] : b3[i - 256];

  // ---- prologue: stage tile 0 into z buffer 0
  {
    const int m0 = tile0 * BM;
    float4 xr[8], hr[10];
    const float4* xg = (const float4*)(x + (size_t)m0 * 256);
#pragma unroll
    for (int k = 0; k < 8; k++) xr[k] = xg[t + k * 256];
    const float4* hg = (const float4*)(h + (size_t)m0 * 320);
#pragma unroll
    for (int k = 0; k < 10; k++) hr[k] = hg[t + k * 256];
    stage_write((uint16_t*)smem, t, xr, hr);
  }
  __syncthreads();

  int cur = 0;
  for (int it = 0; it < NT; ++it) {
    const int m0 = (tile0 + it) * BM;
    uint16_t* zc = (uint16_t*)(smem + cur * ZBYTES);
    uint16_t* zn = (uint16_t*)(smem + (cur ^ 1) * ZBYTES);
    uint16_t* a2 = zc;               // alias: z[cur] dead after GEMM1

    // ---- issue next tile's global loads (consumed after epilogue)
    float4 xr[8], hr[10];
    const bool pf = (it + 1 < NT);
    if (pf) {
      const float4* xg = (const float4*)(x + (size_t)(m0 + BM) * 256);
#pragma unroll
      for (int k = 0; k < 8; k++) xr[k] = xg[t + k * 256];
      const float4* hg = (const float4*)(h + (size_t)(m0 + BM) * 320);
#pragma unroll
      for (int k = 0; k < 10; k++) hr[k] = hg[t + k * 256];
    }

    // ---- GEMM1: a1 = relu(z(32x448) @ W1 + b1)
    {
      f32x4 acc[2][2] = {};
#pragma unroll 2
      for (int kt = 0; kt < 14; kt++) {
        bf16x8 afr[2];
#pragma unroll
        for (int mi = 0; mi < 2; mi++)
          afr[mi] = *(const bf16x8*)&zc[(mi * 16 + lr) * ZP + kt * 32 + lq * 8];
        bf16x8 bfr[2];
#pragma unroll
        for (int nj = 0; nj < 2; nj++)
          bfr[nj] = *(const bf16x8*)&wp[W1P_OFF + ((wid * 2 + nj) * 14 + kt) * 64 + l];
#pragma unroll
        for (int mi = 0; mi < 2; mi++)
#pragma unroll
          for (int nj = 0; nj < 2; nj++)
            acc[mi][nj] = __builtin_amdgcn_mfma_f32_16x16x32_bf16(afr[mi], bfr[nj], acc[mi][nj], 0, 0, 0);
      }
#pragma unroll
      for (int mi = 0; mi < 2; mi++)
#pragma unroll
        for (int nj = 0; nj < 2; nj++) {
          int col = wid * 32 + nj * 16 + lr;
          float bv = bias[col];
#pragma unroll
          for (int r = 0; r < 4; r++)
            a1[(mi * 16 + lq * 4 + r) * AP + col] = f2bf(fmaxf(acc[mi][nj][r] + bv, 0.f));
        }
    }
    __syncthreads();   // B1: a1 visible, z[cur] dead

    // ---- GEMM2: a2 = relu(a1 @ W2 + b2)  (a2 -> z[cur] base, disjoint from a1)
    {
      f32x4 acc[2][2] = {};
#pragma unroll
      for (int kt = 0; kt < 4; kt++) {
        bf16x8 afr[2];
#pragma unroll
        for (int mi = 0; mi < 2; mi++)
          afr[mi] = *(const bf16x8*)&a1[(mi * 16 + lr) * AP + kt * 32 + lq * 8];
        bf16x8 bfr[2];
#pragma unroll
        for (int nj = 0; nj < 2; nj++)
          bfr[nj] = *(const bf16x8*)&wp[W2P_OFF + ((wid * 2 + nj) * 4 + kt) * 64 + l];
#pragma unroll
        for (int mi = 0; mi < 2; mi++)
#pragma unroll
          for (int nj = 0; nj < 2; nj++)
            acc[mi][nj] = __builtin_amdgcn_mfma_f32_16x16x32_bf16(afr[mi], bfr[nj], acc[mi][nj], 0, 0, 0);
      }
#pragma unroll
      for (int mi = 0; mi < 2; mi++)
#pragma unroll
        for (int nj = 0; nj < 2; nj++) {
          int col = wid * 32 + nj * 16 + lr;
          float bv = bias[128 + col];
#pragma unroll
          for (int r = 0; r < 4; r++)
            a2[(mi * 16 + lq * 4 + r) * AP + col] = f2bf(fmaxf(acc[mi][nj][r] + bv, 0.f));
        }
    }
    __syncthreads();   // B2: a2 visible

    // ---- epilogue x prefetch (hides under GEMM3)
    float2 xv[2][2][4];
#pragma unroll
    for (int mi = 0; mi < 2; mi++)
#pragma unroll
      for (int nj = 0; nj < 2; nj++) {
        int colc = wid * 32 + nj * 16 + lr;
#pragma unroll
        for (int r = 0; r < 4; r++) {
          int grow = m0 + mi * 16 + lq * 4 + r;
          xv[mi][nj][r] = *(const float2*)(x + (size_t)grow * 256 + 2 * colc);
        }
      }

    // ---- GEMM3: st = a2 @ W3 + b3
    f32x4 acc3[2][4] = {};
#pragma unroll
    for (int kt = 0; kt < 4; kt++) {
      bf16x8 afr[2];
#pragma unroll
      for (int mi = 0; mi < 2; mi++)
        afr[mi] = *(const bf16x8*)&a2[(mi * 16 + lr) * AP + kt * 32 + lq * 8];
      bf16x8 bfr[4];
#pragma unroll
      for (int nj = 0; nj < 2; nj++) {
        bfr[nj]     = *(const bf16x8*)&wp[W3P_OFF + ((wid * 2 + nj) * 4 + kt) * 64 + l];
        bfr[nj + 2] = *(const bf16x8*)&wp[W3P_OFF + ((8 + wid * 2 + nj) * 4 + kt) * 64 + l];
      }
#pragma unroll
      for (int mi = 0; mi < 2; mi++)
#pragma unroll
        for (int nj = 0; nj < 4; nj++)
          acc3[mi][nj] = __builtin_amdgcn_mfma_f32_16x16x32_bf16(afr[mi], bfr[nj], acc3[mi][nj], 0, 0, 0);
    }

    // ---- epilogue: tanh/exp, y write, log_det
    float lp[2][4];
#pragma unroll
    for (int mi = 0; mi < 2; mi++)
#pragma unroll
      for (int r = 0; r < 4; r++) lp[mi][r] = 0.f;

#pragma unroll
    for (int mi = 0; mi < 2; mi++)
#pragma unroll
      for (int nj = 0; nj < 2; nj++) {
        int colc = wid * 32 + nj * 16 + lr;
        float bs = bias[256 + colc];
        float bt = bias[384 + colc];
#pragma unroll
        for (int r = 0; r < 4; r++) {
          int grow = m0 + mi * 16 + lq * 4 + r;
          float sv = tanh_fast(acc3[mi][nj][r] + bs);
          float tv = acc3[mi][nj + 2][r] + bt;
          lp[mi][r] += sv;
          float2 o;
          o.x = xv[mi][nj][r].x;
          o.y = xv[mi][nj][r].y * __expf(sv) + tv;
          *(float2*)(y + (size_t)grow * 256 + 2 * colc) = o;
        }
      }

#pragma unroll
    for (int mi = 0; mi < 2; mi++)
#pragma unroll
      for (int r = 0; r < 4; r++) {
        float v = lp[mi][r];
        v += __shfl_xor(v, 1);
        v += __shfl_xor(v, 2);
        v += __shfl_xor(v, 4);
        v += __shfl_xor(v, 8);
        if (lr == 0) lsum[wid * BM + mi * 16 + lq * 4 + r] = v;
      }
    __syncthreads();   // B3: lsum visible, all a2 reads done
    if (t < BM) ldet[m0 + t] = lsum[t] + lsum[BM + t] + lsum[2 * BM + t] + lsum[3 * BM + t];

    // ---- complete stage of tile it+1 into z[next]
    if (pf) stage_write(zn, t, xr, hr);
    __syncthreads();   // B4: z[next] staged
    cur ^= 1;
  }
}

extern "C" void kernel_launch(void* const* d_in, const int* in_sizes, int n_in,
                              void* d_out, int out_size, void* d_ws, size_t ws_size,
                              hipStream_t stream) {
  const float* x  = (const float*)d_in[0];
  const float* h  = (const float*)d_in[1];
  const float* W1 = (const float*)d_in[2];
  const float* b1 = (const float*)d_in[3];
  const float* W2 = (const float*)d_in[4];
  const float* b2 = (const float*)d_in[5];
  const float* W3 = (const float*)d_in[6];
  const float* b3 = (const float*)d_in[7];
  float* y    = (float*)d_out;
  float* ldet = y + (size_t)B_ROWS * 256;
  uint4* wp   = (uint4*)d_ws;

  prepack_kernel<<<52, 256, 0, stream>>>(W1, W2, W3, wp);

  (void)hipFuncSetAttribute((const void*)fused_kernel,
                            hipFuncAttributeMaxDynamicSharedMemorySize, LDS_TOTAL);
  fused_kernel<<<GRID, 256, LDS_TOTAL, stream>>>(x, h, b1, b2, b3, wp, y, ldet);
}

// Round 6
// 180.959 us; speedup vs baseline: 1.3200x; 1.3200x over previous
//
#include <hip/hip_runtime.h>
#include <stdint.h>

typedef __attribute__((ext_vector_type(8))) short bf16x8;
typedef __attribute__((ext_vector_type(4))) float f32x4;

#define B_ROWS 131072
#define BM 16
#define ZP 456   // z row pitch in bf16 (448 + 8 pad)
#define AP 136   // a1 row pitch in bf16 (128 + 8 pad)

#define Z_BYTES  (BM * ZP * 2)            // 14592
#define A1_OFF   Z_BYTES                  // 14592
#define A1_BYTES (BM * AP * 2)            // 4352
#define LDET_OFF (A1_OFF + A1_BYTES)      // 18944
#define LDS_TOTAL (LDET_OFF + 64 * 4)     // 19200 -> 8 blocks/CU (153600 <= 163840)

// packed weight fragment offsets (uint4 units)
#define W1P_OFF 0      // 8 nt * 14 kt * 64
#define W2P_OFF 7168   // 8 * 4 * 64
#define W3P_OFF 9216   // 16 * 4 * 64

__device__ inline uint16_t f2bf(float x) {
  uint32_t u = __float_as_uint(x);
  u += 0x7fffu + ((u >> 16) & 1u);   // RNE
  return (uint16_t)(u >> 16);
}

__device__ inline float tanh_fast(float x) {
  x = fminf(fmaxf(x, -15.f), 15.f);
  float e = __expf(2.f * x);
  return (e - 1.f) / (e + 1.f);
}

__global__ void prepack_kernel(const float* __restrict__ W1,
                               const float* __restrict__ W2,
                               const float* __restrict__ W3,
                               uint4* __restrict__ wp) {
  int tid = blockIdx.x * 256 + threadIdx.x;
  if (tid >= 13312) return;
  int l = tid & 63, f = tid >> 6;
  const float* W; int N, kt, nt;
  if (f < 112)      { W = W1; N = 128; int ff = f;       nt = ff / 14; kt = ff - nt * 14; }
  else if (f < 144) { W = W2; N = 128; int ff = f - 112; nt = ff >> 2; kt = ff & 3; }
  else              { W = W3; N = 256; int ff = f - 144; nt = ff >> 2; kt = ff & 3; }
  int k0  = kt * 32 + (l >> 4) * 8;
  int col = nt * 16 + (l & 15);
  uint16_t v[8];
#pragma unroll
  for (int j = 0; j < 8; j++) v[j] = f2bf(W[(size_t)(k0 + j) * N + col]);
  uint4 o;
  o.x = (uint32_t)v[0] | ((uint32_t)v[1] << 16);
  o.y = (uint32_t)v[2] | ((uint32_t)v[3] << 16);
  o.z = (uint32_t)v[4] | ((uint32_t)v[5] << 16);
  o.w = (uint32_t)v[6] | ((uint32_t)v[7] << 16);
  wp[tid] = o;
}

__global__ __launch_bounds__(256, 8) void fused_kernel(
    const float* __restrict__ x, const float* __restrict__ h,
    const float* __restrict__ b1, const float* __restrict__ b2,
    const float* __restrict__ b3, const uint4* __restrict__ wp,
    float* __restrict__ y, float* __restrict__ ldet) {
  extern __shared__ uint8_t smem[];
  uint16_t* zs   = (uint16_t*)smem;             // [16][456]
  uint16_t* a1   = (uint16_t*)(smem + A1_OFF);  // [16][136]
  uint16_t* a2   = zs;                          // alias: z dead after GEMM1 (B1 orders)
  float*    lsum = (float*)(smem + LDET_OFF);   // 64 f32, own region

  const int t  = threadIdx.x;
  const int m0 = blockIdx.x * BM;

  // ---- stage: x even cols -> z[:,0:128] bf16 ; h -> z[:,128:448] bf16
  {
    const float4* xg = (const float4*)(x + (size_t)m0 * 256);
#pragma unroll
    for (int k = 0; k < 4; k++) {
      int idx = t + k * 256;              // 0..1023 = 16 rows * 64 float4
      int row = idx >> 6, c4 = idx & 63;
      float4 v = xg[idx];
      uint32_t p = (uint32_t)f2bf(v.x) | ((uint32_t)f2bf(v.z) << 16);
      *(uint32_t*)&zs[row * ZP + c4 * 2] = p;
    }
    const float4* hg = (const float4*)(h + (size_t)m0 * 320);
#pragma unroll
    for (int k = 0; k < 5; k++) {
      int idx = t + k * 256;              // 0..1279 = 16 rows * 80 float4
      int row = idx / 80, c4 = idx - row * 80;
      float4 v = hg[idx];
      uint2 p;
      p.x = (uint32_t)f2bf(v.x) | ((uint32_t)f2bf(v.y) << 16);
      p.y = (uint32_t)f2bf(v.z) | ((uint32_t)f2bf(v.w) << 16);
      *(uint2*)&zs[row * ZP + 128 + c4 * 4] = p;
    }
  }
  __syncthreads();

  const int wid = t >> 6, l = t & 63;
  const int lr = l & 15, lq = l >> 4;

  // ---- GEMM1: a1 = relu(z(16x448) @ W1 + b1); wave owns 32 cols
  {
    f32x4 acc[2] = {};
#pragma unroll 2
    for (int kt = 0; kt < 14; kt++) {
      bf16x8 afr = *(const bf16x8*)&zs[lr * ZP + kt * 32 + lq * 8];
      bf16x8 bfr0 = *(const bf16x8*)&wp[W1P_OFF + ((wid * 2 + 0) * 14 + kt) * 64 + l];
      bf16x8 bfr1 = *(const bf16x8*)&wp[W1P_OFF + ((wid * 2 + 1) * 14 + kt) * 64 + l];
      acc[0] = __builtin_amdgcn_mfma_f32_16x16x32_bf16(afr, bfr0, acc[0], 0, 0, 0);
      acc[1] = __builtin_amdgcn_mfma_f32_16x16x32_bf16(afr, bfr1, acc[1], 0, 0, 0);
    }
#pragma unroll
    for (int nj = 0; nj < 2; nj++) {
      int col = wid * 32 + nj * 16 + lr;
      float bv = b1[col];
#pragma unroll
      for (int r = 0; r < 4; r++)
        a1[(lq * 4 + r) * AP + col] = f2bf(fmaxf(acc[nj][r] + bv, 0.f));
    }
  }
  __syncthreads();   // B1: a1 visible, z dead

  // ---- GEMM2: a2 = relu(a1 @ W2 + b2)
  {
    f32x4 acc[2] = {};
#pragma unroll
    for (int kt = 0; kt < 4; kt++) {
      bf16x8 afr = *(const bf16x8*)&a1[lr * AP + kt * 32 + lq * 8];
      bf16x8 bfr0 = *(const bf16x8*)&wp[W2P_OFF + ((wid * 2 + 0) * 4 + kt) * 64 + l];
      bf16x8 bfr1 = *(const bf16x8*)&wp[W2P_OFF + ((wid * 2 + 1) * 4 + kt) * 64 + l];
      acc[0] = __builtin_amdgcn_mfma_f32_16x16x32_bf16(afr, bfr0, acc[0], 0, 0, 0);
      acc[1] = __builtin_amdgcn_mfma_f32_16x16x32_bf16(afr, bfr1, acc[1], 0, 0, 0);
    }
    __syncthreads();  // order a1 reads before a2 (zs-region) writes of other waves
#pragma unroll
    for (int nj = 0; nj < 2; nj++) {
      int col = wid * 32 + nj * 16 + lr;
      float bv = b2[col];
#pragma unroll
      for (int r = 0; r < 4; r++)
        a2[(lq * 4 + r) * AP + col] = f2bf(fmaxf(acc[nj][r] + bv, 0.f));
    }
  }
  __syncthreads();   // B2: a2 visible

  // ---- GEMM3: st = a2 @ W3 + b3 ; wave owns s-cols [32w,32w+32) and t-cols +128
  f32x4 acc3[4] = {};
#pragma unroll
  for (int kt = 0; kt < 4; kt++) {
    bf16x8 afr = *(const bf16x8*)&a2[lr * AP + kt * 32 + lq * 8];
    bf16x8 bfrS0 = *(const bf16x8*)&wp[W3P_OFF + ((wid * 2 + 0) * 4 + kt) * 64 + l];
    bf16x8 bfrS1 = *(const bf16x8*)&wp[W3P_OFF + ((wid * 2 + 1) * 4 + kt) * 64 + l];
    bf16x8 bfrT0 = *(const bf16x8*)&wp[W3P_OFF + ((8 + wid * 2 + 0) * 4 + kt) * 64 + l];
    bf16x8 bfrT1 = *(const bf16x8*)&wp[W3P_OFF + ((8 + wid * 2 + 1) * 4 + kt) * 64 + l];
    acc3[0] = __builtin_amdgcn_mfma_f32_16x16x32_bf16(afr, bfrS0, acc3[0], 0, 0, 0);
    acc3[1] = __builtin_amdgcn_mfma_f32_16x16x32_bf16(afr, bfrS1, acc3[1], 0, 0, 0);
    acc3[2] = __builtin_amdgcn_mfma_f32_16x16x32_bf16(afr, bfrT0, acc3[2], 0, 0, 0);
    acc3[3] = __builtin_amdgcn_mfma_f32_16x16x32_bf16(afr, bfrT1, acc3[3], 0, 0, 0);
  }

  // ---- epilogue: s=tanh, y pair-write, log_det partials
  float lp[4] = {0.f, 0.f, 0.f, 0.f};
#pragma unroll
  for (int nj = 0; nj < 2; nj++) {
    int colc = wid * 32 + nj * 16 + lr;   // 0..127
    float bs = b3[colc];
    float bt = b3[128 + colc];
#pragma unroll
    for (int r = 0; r < 4; r++) {
      int grow = m0 + lq * 4 + r;
      float sv = tanh_fast(acc3[nj][r] + bs);
      float tv = acc3[nj + 2][r] + bt;
      lp[r] += sv;
      const float2 xv = *(const float2*)(x + (size_t)grow * 256 + 2 * colc);
      float2 o;
      o.x = xv.x;                            // exact pass-through
      o.y = xv.y * __expf(sv) + tv;
      *(float2*)(y + (size_t)grow * 256 + 2 * colc) = o;
    }
  }

  // log_det: reduce 16 lanes (col dim, 32 cols per wave) then combine 4 waves
#pragma unroll
  for (int r = 0; r < 4; r++) {
    float v = lp[r];
    v += __shfl_xor(v, 1);
    v += __shfl_xor(v, 2);
    v += __shfl_xor(v, 4);
    v += __shfl_xor(v, 8);
    if (lr == 0) lsum[wid * BM + lq * 4 + r] = v;
  }
  __syncthreads();
  if (t < BM)
    ldet[m0 + t] = lsum[t] + lsum[BM + t] + lsum[2 * BM + t] + lsum[3 * BM + t];
}

extern "C" void kernel_launch(void* const* d_in, const int* in_sizes, int n_in,
                              void* d_out, int out_size, void* d_ws, size_t ws_size,
                              hipStream_t stream) {
  const float* x  = (const float*)d_in[0];
  const float* h  = (const float*)d_in[1];
  const float* W1 = (const float*)d_in[2];
  const float* b1 = (const float*)d_in[3];
  const float* W2 = (const float*)d_in[4];
  const float* b2 = (const float*)d_in[5];
  const float* W3 = (const float*)d_in[6];
  const float* b3 = (const float*)d_in[7];
  float* y    = (float*)d_out;
  float* ldet = y + (size_t)B_ROWS * 256;
  uint4* wp   = (uint4*)d_ws;

  prepack_kernel<<<52, 256, 0, stream>>>(W1, W2, W3, wp);

  (void)hipFuncSetAttribute((const void*)fused_kernel,
                            hipFuncAttributeMaxDynamicSharedMemorySize, LDS_TOTAL);
  fused_kernel<<<B_ROWS / BM, 256, LDS_TOTAL, stream>>>(x, h, b1, b2, b3, wp, y, ldet);
}